// Round 20
// baseline (34.019 us; speedup 1.0000x reference)
//
#include <hip/hip_runtime.h>
#include <stdint.h>

#define NA   3
#define KCH  8        // 5 + NUM_CLASSES
#define BLK  512
#define NWV  (BLK / 64)
#define NB   2048     // stage-1 bins: key16 >> 5
#define QCAP 512
#define HCAP 3072     // per-half publish cap (entries; expected ~912, 24 sigma)
#define CCAP 6400     // LDS merged compact cap (entries)
#define LKEY 0xBFA8u  // raw-obj key16 rung (obj>1.3125, ~9.5% of N(0,1)); runtime-verified

#define LOG2E 1.4426950408889634f
#define LN2   0.6931471805599453f

struct ScaleParams {
  const float*   pred;    // (B, 24, H, W)
  const float*   boxes;   // (B, N, 4)
  const int*     labels;  // (B, N)
  const uint8_t* pos;     // (B, N) bool
  const uint8_t* neg;     // (B, N) bool
  int HW;
};

__device__ __forceinline__ float fexp2(float x) { return __builtin_amdgcn_exp2f(x); }
__device__ __forceinline__ float flog2(float x) { return __builtin_amdgcn_logf(x); }

// logaddexp(0,x) = max(x,0) + log1p(exp(-|x|)); native exp2/log2, ~1e-6 rel
__device__ __forceinline__ float softplus_fast(float x) {
  const float t = fexp2(-fabsf(x) * LOG2E);
  return fmaxf(x, 0.f) + flog2(1.f + t) * LN2;
}

__device__ __forceinline__ float sl1f(float d) {
  float ad = fabsf(d);
  return (ad < 1.f) ? 0.5f * d * d : ad - 0.5f;
}

// order-preserving float->uint key (larger float => larger key)
__device__ __forceinline__ unsigned fkey(unsigned u) {
  return (u & 0x80000000u) ? ~u : (u | 0x80000000u);
}
__device__ __forceinline__ unsigned funkey(unsigned k) {
  return (k & 0x80000000u) ? (k & 0x7FFFFFFFu) : ~k;
}
// softplus of obj reconstructed from 16-bit key (interval midpoint)
__device__ __forceinline__ float sp16(unsigned k16) {
  return softplus_fast(__uint_as_float(funkey((k16 << 16) | 0x8000u)));
}

// agent-scope (device-coherent, cache-bypassing) scalar access — no fences
__device__ __forceinline__ unsigned aload(const unsigned* p) {
  return __hip_atomic_load(p, __ATOMIC_RELAXED, __HIP_MEMORY_SCOPE_AGENT);
}
__device__ __forceinline__ void astore(unsigned* p, unsigned v) {
  __hip_atomic_store(p, v, __ATOMIC_RELAXED, __HIP_MEMORY_SCOPE_AGENT);
}

struct __align__(16) RowShared {
  unsigned short compact[CCAP];  // 12.8 KB: keys > LKEY (0 = pad/skip)
  unsigned hc[NB];               // 8 KB: stage-1 counts
  int      queue[QCAP];          // 2 KB: pos-anchor indices
  int      sh_qn, sh_nc;
  int      iwav[NWV];
  float    fscr[NWV];
  float    wred[NWV][4];
  int      sh_dig, sh_krem;
  float    sh_sa, sh_avg;
  int      sh_flag;
  unsigned sh_sib[8];
  unsigned c32[32];
  float    s32[32];
};

__device__ __forceinline__ float blockSum(float v, float* scr) {
  #pragma unroll
  for (int off = 32; off > 0; off >>= 1) v += __shfl_down(v, off);
  const int lane = threadIdx.x & 63, w = threadIdx.x >> 6;
  __syncthreads();
  if (lane == 0) scr[w] = v;
  __syncthreads();
  float r = 0.f;
  #pragma unroll
  for (int i = 0; i < NWV; ++i) r += scr[i];
  return r;
}

// counts-only suffix select over NB bins, 4 bins/thread. Block-uniform.
__device__ __forceinline__ void selectBin1(const unsigned* cb, int krem_in,
                                           RowShared& S) {
  const int t = threadIdx.x, lane = t & 63, w = t >> 6;
  const int c_t = (int)(cb[0] + cb[1] + cb[2] + cb[3]);
  int ci = c_t;
  #pragma unroll
  for (int off = 1; off < 64; off <<= 1) {
    const int co = __shfl_down(ci, off);
    if (lane + off < 64) ci += co;
  }
  __syncthreads();
  if (lane == 0) S.iwav[w] = ci;
  __syncthreads();
  int ac = 0;
  #pragma unroll
  for (int w2 = 0; w2 < NWV; ++w2) if (w2 > w) ac += S.iwav[w2];
  int cum_c = (ci - c_t) + ac;
  #pragma unroll
  for (int q = 3; q >= 0; --q) {
    const int cq = (int)cb[q];
    if (cq > 0 && cum_c < krem_in && krem_in <= cum_c + cq) {
      S.sh_dig  = t * 4 + q;
      S.sh_krem = krem_in - cum_c;
    }
    cum_c += cq;
  }
  __syncthreads();
}

// stage-2: 32 sub-bins of bin1 -> final selected-sum given sum-above sa1.
__device__ __forceinline__ float stage2_sel(int krem1, float sa1, RowShared& S) {
  const int t = threadIdx.x;
  if (t < 64) {
    const int cc = (t < 32) ? (int)S.c32[t] : 0;
    const float ss = (t < 32) ? S.s32[t] : 0.f;
    int ci = cc; float si = ss;
    #pragma unroll
    for (int off = 1; off < 64; off <<= 1) {
      const int   co = __shfl_down(ci, off);
      const float so = __shfl_down(si, off);
      if ((t & 63) + off < 64) { ci += co; si += so; }
    }
    const int   above_c = ci - cc;
    const float above_s = si - ss;
    if (t < 32 && cc > 0 && above_c < krem1 && krem1 <= above_c + cc) {
      S.sh_krem = krem1 - above_c;
      S.sh_sa   = sa1 + above_s;
      S.sh_avg  = ss / (float)cc;        // tie-bin average (key-exact)
    }
  }
  __syncthreads();
  return S.sh_sa + (float)S.sh_krem * S.sh_avg;
}

// Normal path: selection over m LDS compact entries (zeros skipped).
__device__ float select_compact(int m, int k, RowShared& S) {
  const int t = threadIdx.x;
  for (int i = t; i < NB; i += BLK) S.hc[i] = 0u;
  __syncthreads();
  for (int i = t; i < m; i += BLK) {
    const unsigned k16 = S.compact[i];
    if (k16) atomicAdd(&S.hc[k16 >> 5], 1u);
  }
  __syncthreads();
  unsigned cb[4];
  #pragma unroll
  for (int q = 0; q < 4; ++q) cb[q] = S.hc[4 * t + q];
  selectBin1(cb, k, S);
  const int bin1 = S.sh_dig, krem1 = S.sh_krem;
  if (t < 32) { S.c32[t] = 0u; S.s32[t] = 0.f; }
  __syncthreads();
  float sgt = 0.f;
  for (int i = t; i < m; i += BLK) {
    const unsigned k16 = S.compact[i];
    if (!k16) continue;
    const int kb = (int)(k16 >> 5);
    if (kb > bin1) sgt += sp16(k16);
    else if (kb == bin1) {
      atomicAdd(&S.c32[k16 & 31u], 1u);
      atomicAdd(&S.s32[k16 & 31u], sp16(k16));
    }
  }
  __syncthreads();
  const float t_sgt = blockSum(sgt, S.fscr);
  return stage2_sel(krem1, t_sgt, S);
}

// Rare exact fallback: full-row global rescan (unfiltered), 2 sweeps.
template<int HW>
__device__ float select_full(const ScaleParams& P, int b, int k, RowShared& S) {
  constexpr int N = 3 * HW;
  const int t = threadIdx.x;
  const float* predb = P.pred + (size_t)b * (NA * KCH) * HW;
  const size_t row = (size_t)b * N;
  for (int i = t; i < NB; i += BLK) S.hc[i] = 0u;
  __syncthreads();
  for (int c8 = t * 8; c8 < N; c8 += BLK * 8) {
    const int a = (c8 >= HW) + (c8 >= 2 * HW);
    const int cell = c8 - a * HW;
    const float* po = predb + (size_t)a * KCH * HW + 4 * HW + cell;
    const float4 o0 = *(const float4*)po;
    const float4 o1 = *(const float4*)(po + 4);
    const uint2 nmv = *(const uint2*)(P.neg + row + c8);
    #pragma unroll
    for (int q = 0; q < 8; ++q) {
      const unsigned nm = ((q < 4) ? (nmv.x >> (8 * q))
                                   : (nmv.y >> (8 * (q - 4)))) & 0xFFu;
      if (nm) {
        const float obj = (q < 4) ? (&o0.x)[q] : (&o1.x)[q - 4];
        atomicAdd(&S.hc[(fkey(__float_as_uint(obj)) >> 16) >> 5], 1u);
      }
    }
  }
  __syncthreads();
  unsigned cb[4];
  #pragma unroll
  for (int q = 0; q < 4; ++q) cb[q] = S.hc[4 * t + q];
  selectBin1(cb, k, S);
  const int bin1 = S.sh_dig, krem1 = S.sh_krem;
  if (t < 32) { S.c32[t] = 0u; S.s32[t] = 0.f; }
  __syncthreads();
  float sgt = 0.f;
  for (int c8 = t * 8; c8 < N; c8 += BLK * 8) {
    const int a = (c8 >= HW) + (c8 >= 2 * HW);
    const int cell = c8 - a * HW;
    const float* po = predb + (size_t)a * KCH * HW + 4 * HW + cell;
    const float4 o0 = *(const float4*)po;
    const float4 o1 = *(const float4*)(po + 4);
    const uint2 nmv = *(const uint2*)(P.neg + row + c8);
    #pragma unroll
    for (int q = 0; q < 8; ++q) {
      const unsigned nm = ((q < 4) ? (nmv.x >> (8 * q))
                                   : (nmv.y >> (8 * (q - 4)))) & 0xFFu;
      if (nm) {
        const float obj = (q < 4) ? (&o0.x)[q] : (&o1.x)[q - 4];
        const unsigned k16 = fkey(__float_as_uint(obj)) >> 16;
        const int kb = (int)(k16 >> 5);
        if (kb > bin1) sgt += sp16(k16);
        else if (kb == bin1) {
          atomicAdd(&S.c32[k16 & 31u], 1u);
          atomicAdd(&S.s32[k16 & 31u], sp16(k16));
        }
      }
    }
  }
  __syncthreads();
  const float t_sgt = blockSum(sgt, S.fscr);
  return stage2_sel(krem1, t_sgt, S);
}

// Sweep [c0, c0+NLOC): compact >LKEY candidates (batched append), nneg via
// popcount, pos queue + dense pos work. red = {nneg, posobj, ce, loc}.
template<int HW, int NLOC>
__device__ __forceinline__ int scan_range(
    const ScaleParams& P, int b, int c0, RowShared& S, float red[4]) {
  constexpr int ITER = (NLOC + BLK * 8 - 1) / (BLK * 8);
  const int t = threadIdx.x;
  if (t == 0) { S.sh_qn = 0; S.sh_nc = 0; }
  __syncthreads();

  const float* predb = P.pred + (size_t)b * (NA * KCH) * HW;
  const size_t row = (size_t)b * (3 * HW);
  float nneg = 0.f;

  float4 o0[ITER], o1[ITER];
  uint2  pmv[ITER], nmv[ITER];
  #pragma unroll
  for (int it = 0; it < ITER; ++it) {
    const int c8 = c0 + it * (BLK * 8) + t * 8;
    if (c8 < c0 + NLOC) {
      const int a = (c8 >= HW) + (c8 >= 2 * HW);
      const int cell = c8 - a * HW;
      const float* po = predb + (size_t)a * KCH * HW + 4 * HW + cell;
      o0[it]  = *(const float4*)po;
      o1[it]  = *(const float4*)(po + 4);
      pmv[it] = *(const uint2*)(P.pos + row + c8);
      nmv[it] = *(const uint2*)(P.neg + row + c8);
    }
  }
  #pragma unroll
  for (int it = 0; it < ITER; ++it) {
    const int c8 = c0 + it * (BLK * 8) + t * 8;
    if (c8 < c0 + NLOC) {
      const unsigned long long nm64 =
          ((unsigned long long)nmv[it].y << 32) | nmv[it].x;
      nneg += (float)__popcll(nm64);
      unsigned k16s[8], cmask = 0u;
      #pragma unroll
      for (int q = 0; q < 8; ++q) {
        const unsigned nm = ((q < 4) ? (nmv[it].x >> (8 * q))
                                     : (nmv[it].y >> (8 * (q - 4)))) & 0xFFu;
        const unsigned pm = ((q < 4) ? (pmv[it].x >> (8 * q))
                                     : (pmv[it].y >> (8 * (q - 4)))) & 0xFFu;
        unsigned k16 = 0u;
        if (nm) {
          k16 = fkey(__float_as_uint((q < 4) ? (&o0[it].x)[q]
                                             : (&o1[it].x)[q - 4])) >> 16;
          if (k16 > LKEY) cmask |= (1u << q);
        }
        k16s[q] = k16;                        // compile-time index: registers
        if (pm) {
          const int idx = atomicAdd(&S.sh_qn, 1);
          if (idx < QCAP) S.queue[idx] = c8 + q;
        }
      }
      if (cmask) {                            // batched append: 1 atomic/8 elems
        const int ci = atomicAdd(&S.sh_nc, (int)__popc(cmask));
        #pragma unroll
        for (int q = 0; q < 8; ++q)
          if ((cmask >> q) & 1u) {
            const int p = ci + (int)__popc(cmask & ((1u << q) - 1u));
            if (p < CCAP) S.compact[p] = (unsigned short)k16s[q];
          }
      }
    }
  }
  __syncthreads();
  const int npos = S.sh_qn;
  const int qn = min(npos, QCAP);

  float posobj = 0.f, ce = 0.f, loc = 0.f;
  for (int i = t; i < qn; i += BLK) {
    const int j = S.queue[i];
    const int a = (j >= HW) + (j >= 2 * HW);
    const int cell = j - a * HW;
    const float* pa = predb + (size_t)a * KCH * HW;
    posobj += softplus_fast(-pa[4 * HW + cell]);     // sp(x)-x == sp(-x)
    const float c0f = pa[5 * HW + cell];
    const float c1f = pa[6 * HW + cell];
    const float c2f = pa[7 * HW + cell];
    const float m = fmaxf(fmaxf(c0f, c1f), c2f);
    const float e = fexp2((c0f - m) * LOG2E) + fexp2((c1f - m) * LOG2E)
                  + fexp2((c2f - m) * LOG2E);
    const float lse = m + flog2(e) * LN2;
    const int lab = P.labels[row + j];
    ce += lse - ((lab == 0) ? c0f : (lab == 1) ? c1f : c2f);
    const float4 bx = *(const float4*)(P.boxes + (size_t)(row + j) * 4);
    loc += sl1f(pa[0 * HW + cell] - bx.x) + sl1f(pa[1 * HW + cell] - bx.y)
         + sl1f(pa[2 * HW + cell] - bx.z) + sl1f(pa[3 * HW + cell] - bx.w);
  }

  {
    float v[4] = {nneg, posobj, ce, loc};
    #pragma unroll
    for (int i = 0; i < 4; ++i) {
      #pragma unroll
      for (int off = 32; off > 0; off >>= 1) v[i] += __shfl_down(v[i], off);
    }
    const int lane = t & 63, w = t >> 6;
    __syncthreads();
    if (lane == 0) {
      #pragma unroll
      for (int i = 0; i < 4; ++i) S.wred[w][i] = v[i];
    }
    __syncthreads();
  }
  #pragma unroll
  for (int i = 0; i < 4; ++i) {
    float acc = 0.f;
    #pragma unroll
    for (int w2 = 0; w2 < NWV; ++w2) acc += S.wred[w2][i];
    red[i] = acc;
  }
  return npos;
}

// s1/s2 whole row.
template<int HW>
__device__ __forceinline__ void row_whole(const ScaleParams& P, int b,
                                          float* part, RowShared& S) {
  float red[4];
  const int npos = scan_range<HW, 3 * HW>(P, b, 0, S, red);
  const int nc = S.sh_nc;
  const int k = min(3 * npos, (int)red[0]);
  float sel = 0.f;
  if (k > 0) {
    if (nc <= CCAP && nc >= k) sel = select_compact(min(nc, CCAP), k, S);
    else                       sel = select_full<HW>(P, b, k, S);
  }
  if (threadIdx.x == 0) {
    const float denom = (float)max(npos, 1);
    part[0] = (red[1] + sel) / denom;
    part[1] = (npos > 0) ? red[2] / denom : 0.f;
    part[2] = (npos > 0) ? red[3] / (denom * 4.f) : 0.f;
  }
}

// s0 half: scan 9600 elems; publish compact+scalars (agent-scope stores, no
// fences); per-row ticket; last-arriving half merges and finishes the row.
__device__ bool row_s0_half(
    const ScaleParams& p0, int b, int half,
    unsigned* g_cmp, unsigned* g_sc, unsigned* g_tick,
    float* part, RowShared& S) {
  constexpr int HW = 6400, NLOC = 9600;
  float red[4];
  const int npos = scan_range<HW, NLOC>(p0, b, half * NLOC, S, red);
  const int nc = S.sh_nc;
  const int t = threadIdx.x;
  const int ncs = min(nc, HCAP);

  if (t == 0 && (ncs & 1)) S.compact[ncs] = 0;     // pad odd publish tail
  __syncthreads();
  const size_t hid = (size_t)b * 2 + half;
  unsigned* cmp = g_cmp + hid * (HCAP / 2);
  for (int i = t; i < (ncs + 1) / 2; i += BLK)
    astore(&cmp[i], (unsigned)S.compact[2 * i] |
                    ((unsigned)S.compact[2 * i + 1] << 16));
  if (t == 0) {
    unsigned* sc = g_sc + hid * 8;
    astore(&sc[0], (unsigned)npos);
    astore(&sc[1], __float_as_uint(red[0]));
    astore(&sc[2], __float_as_uint(red[1]));
    astore(&sc[3], __float_as_uint(red[2]));
    astore(&sc[4], __float_as_uint(red[3]));
    astore(&sc[5], (unsigned)nc);
  }
  __syncthreads();                       // drains all agent-scope stores
  if (t == 0) {
    const unsigned old = __hip_atomic_fetch_add(
        &g_tick[b], 1u, __ATOMIC_ACQ_REL, __HIP_MEMORY_SCOPE_AGENT);
    S.sh_flag = (old == 1u) ? 1 : 0;
  }
  __syncthreads();
  if (!S.sh_flag) return false;

  // ---- finisher: merge sibling (agent-scope loads, L3-coherent) ----
  const size_t oid = (size_t)b * 2 + (half ^ 1);
  if (t < 6) S.sh_sib[t] = aload(g_sc + oid * 8 + t);
  __syncthreads();
  const int   npos2 = (int)S.sh_sib[0];
  const float nneg2 = __uint_as_float(S.sh_sib[1]);
  const float po2   = __uint_as_float(S.sh_sib[2]);
  const float ce2   = __uint_as_float(S.sh_sib[3]);
  const float lc2   = __uint_as_float(S.sh_sib[4]);
  const int   nc2   = (int)S.sh_sib[5];
  const int   nc2s  = min(nc2, HCAP);
  const unsigned* cmp2 = g_cmp + oid * (HCAP / 2);
  const int base = ncs;
  for (int i = t; i < (nc2s + 1) / 2; i += BLK) {
    const unsigned w = aload(&cmp2[i]);
    const int p = base + 2 * i;
    if (p < CCAP)     S.compact[p]     = (unsigned short)(w & 0xFFFFu);
    if (p + 1 < CCAP) S.compact[p + 1] = (unsigned short)(w >> 16);
  }
  __syncthreads();

  const int   npos_t = npos + npos2;
  const float nneg_t = red[0] + nneg2;
  const float po_t   = red[1] + po2;
  const float ce_t   = red[2] + ce2;
  const float lc_t   = red[3] + lc2;
  const int   abv_t  = nc + nc2;
  const int   m      = min(base + 2 * ((nc2s + 1) / 2), CCAP);

  const int k = min(3 * npos_t, (int)nneg_t);
  float sel = 0.f;
  if (k > 0) {
    if (nc <= HCAP && nc2 <= HCAP && abv_t >= k)
      sel = select_compact(m, k, S);
    else
      sel = select_full<HW>(p0, b, k, S);    // rare exact fallback
  }
  if (t == 0) {
    const float denom = (float)max(npos_t, 1);
    part[0] = (po_t + sel) / denom;
    part[1] = (npos_t > 0) ? ce_t / denom : 0.f;
    part[2] = (npos_t > 0) ? lc_t / (denom * 4.f) : 0.f;
  }
  return true;
}

__global__ void k_zero(unsigned* g_tick, int B, unsigned* done) {
  for (int i = threadIdx.x; i < B; i += blockDim.x) g_tick[i] = 0u;
  if (threadIdx.x == 0) *done = 0u;
}

__global__ __launch_bounds__(BLK) void k_row(
    ScaleParams p0, ScaleParams p1, ScaleParams p2, int B, int R, float invB,
    unsigned* g_cmp, unsigned* g_sc, unsigned* g_tick,
    float* g_part, unsigned* done, float* out) {
  __shared__ RowShared S;
  const int bid = blockIdx.x;
  bool emit = true;
  if (bid < 2 * B) {                     // s0 halves first (heaviest)
    const int b = bid >> 1, half = bid & 1;
    emit = row_s0_half(p0, b, half, g_cmp, g_sc, g_tick,
                       g_part + (size_t)b * 4, S);
  } else if (bid < 3 * B) {
    const int b = bid - 2 * B;
    row_whole<1600>(p1, b, g_part + (size_t)(B + b) * 4, S);
  } else {
    const int b = bid - 3 * B;
    row_whole<400>(p2, b, g_part + (size_t)(2 * B + b) * 4, S);
  }
  if (!emit) return;

  // ---- proven round-16 emit/reduce protocol (t0-only fence + 1-word ticket)
  if (threadIdx.x == 0) {
    __threadfence();
    const unsigned old = atomicAdd(done, 1u);
    S.sh_flag = (old == (unsigned)(R - 1)) ? 1 : 0;
  }
  __syncthreads();
  if (S.sh_flag) {
    __threadfence();
    const int t = threadIdx.x;
    float o = 0.f, c = 0.f, l = 0.f;
    for (int i = t; i < R; i += BLK) {
      o += g_part[i * 4 + 0];
      c += g_part[i * 4 + 1];
      l += g_part[i * 4 + 2];
    }
    o = blockSum(o, S.fscr);
    c = blockSum(c, S.fscr);
    l = blockSum(l, S.fscr);
    if (t == 0) {
      out[0] = (o + c + l) * invB;
      out[1] = o * invB;
      out[2] = c * invB;
      out[3] = l * invB;
    }
  }
}

extern "C" void kernel_launch(void* const* d_in, const int* in_sizes, int n_in,
                              void* d_out, int out_size, void* d_ws, size_t ws_size,
                              hipStream_t stream) {
  (void)n_in; (void)out_size; (void)ws_size;

  const int HW0 = 80 * 80, HW1 = 40 * 40, HW2 = 20 * 20;
  const int B = in_sizes[0] / (NA * KCH * HW0);
  const int R = 3 * B;
  const float invB = 1.f / (float)B;

  ScaleParams p0{(const float*)d_in[0],  (const float*)d_in[1],
                 (const int*)d_in[2],    (const uint8_t*)d_in[3],
                 (const uint8_t*)d_in[4], HW0};
  ScaleParams p1{(const float*)d_in[5],  (const float*)d_in[6],
                 (const int*)d_in[7],    (const uint8_t*)d_in[8],
                 (const uint8_t*)d_in[9], HW1};
  ScaleParams p2{(const float*)d_in[10], (const float*)d_in[11],
                 (const int*)d_in[12],   (const uint8_t*)d_in[13],
                 (const uint8_t*)d_in[14], HW2};

  float* out = (float*)d_out;

  // workspace layout (256B-aligned sections)
  char* w = (char*)d_ws;
  unsigned* done   = (unsigned*)w;  w += 256;
  unsigned* g_tick = (unsigned*)w;  w += (((size_t)B * 4 + 255) & ~255ull);
  float*    g_part = (float*)w;     w += (((size_t)R * 16 + 255) & ~255ull);
  unsigned* g_sc   = (unsigned*)w;  w += (((size_t)B * 2 * 8 * 4 + 255) & ~255ull);
  unsigned* g_cmp  = (unsigned*)w;  w += (size_t)B * 2 * (HCAP / 2) * 4;

  k_zero<<<1, 256, 0, stream>>>(g_tick, B, done);
  k_row<<<4 * B, BLK, 0, stream>>>(p0, p1, p2, B, R, invB,
                                   g_cmp, g_sc, g_tick, g_part, done, out);
}

// Round 21
// 30.776 us; speedup vs baseline: 1.1054x; 1.1054x over previous
//
#include <hip/hip_runtime.h>
#include <stdint.h>

#define NA   3
#define KCH  8        // 5 + NUM_CLASSES
#define BLK  512
#define NWV  (BLK / 64)
#define NB   2048     // stage-1 bins: key16 >> 5
#define QCAP 512
#define CCAP 4096     // compact cap (expected ~1733 for s0, +57 sigma)
#define LKEY 0xBFA8u  // raw-obj key16 rung (obj>1.3125, ~9.5% of N(0,1)); runtime-verified

#define LOG2E 1.4426950408889634f
#define LN2   0.6931471805599453f

struct ScaleParams {
  const float*   pred;    // (B, 24, H, W)
  const float*   boxes;   // (B, N, 4)
  const int*     labels;  // (B, N)
  const uint8_t* pos;     // (B, N) bool
  const uint8_t* neg;     // (B, N) bool
  int HW;
};

__device__ __forceinline__ float fexp2(float x) { return __builtin_amdgcn_exp2f(x); }
__device__ __forceinline__ float flog2(float x) { return __builtin_amdgcn_logf(x); }

// logaddexp(0,x) = max(x,0) + log1p(exp(-|x|)); native exp2/log2, ~1e-6 rel
__device__ __forceinline__ float softplus_fast(float x) {
  const float t = fexp2(-fabsf(x) * LOG2E);
  return fmaxf(x, 0.f) + flog2(1.f + t) * LN2;
}

__device__ __forceinline__ float sl1f(float d) {
  float ad = fabsf(d);
  return (ad < 1.f) ? 0.5f * d * d : ad - 0.5f;
}

// order-preserving float->uint key (larger float => larger key)
__device__ __forceinline__ unsigned fkey(unsigned u) {
  return (u & 0x80000000u) ? ~u : (u | 0x80000000u);
}
__device__ __forceinline__ unsigned funkey(unsigned k) {
  return (k & 0x80000000u) ? (k & 0x7FFFFFFFu) : ~k;
}
// softplus of obj reconstructed from 16-bit key (interval midpoint)
__device__ __forceinline__ float sp16(unsigned k16) {
  return softplus_fast(__uint_as_float(funkey((k16 << 16) | 0x8000u)));
}

struct __align__(16) RowShared {
  unsigned short compact[CCAP];  // 8 KB: keys > LKEY
  unsigned hc[NB];               // 8 KB: stage-1 counts (selection only)
  int      queue[QCAP];          // 2 KB: pos-anchor indices
  int      sh_qn, sh_nc;
  int      iwav[NWV];
  float    fscr[NWV];
  float    wred[NWV][4];
  int      sh_dig, sh_krem;
  float    sh_sa, sh_avg;
  int      sh_flag;
  unsigned c32[32];
  float    s32[32];
};

__device__ __forceinline__ float blockSum(float v, float* scr) {
  #pragma unroll
  for (int off = 32; off > 0; off >>= 1) v += __shfl_down(v, off);
  const int lane = threadIdx.x & 63, w = threadIdx.x >> 6;
  __syncthreads();
  if (lane == 0) scr[w] = v;
  __syncthreads();
  float r = 0.f;
  #pragma unroll
  for (int i = 0; i < NWV; ++i) r += scr[i];
  return r;
}

// counts-only suffix select over NB bins, 4 bins/thread. Block-uniform.
__device__ __forceinline__ void selectBin1(const unsigned* cb, int krem_in,
                                           RowShared& S) {
  const int t = threadIdx.x, lane = t & 63, w = t >> 6;
  const int c_t = (int)(cb[0] + cb[1] + cb[2] + cb[3]);
  int ci = c_t;
  #pragma unroll
  for (int off = 1; off < 64; off <<= 1) {
    const int co = __shfl_down(ci, off);
    if (lane + off < 64) ci += co;
  }
  __syncthreads();
  if (lane == 0) S.iwav[w] = ci;
  __syncthreads();
  int ac = 0;
  #pragma unroll
  for (int w2 = 0; w2 < NWV; ++w2) if (w2 > w) ac += S.iwav[w2];
  int cum_c = (ci - c_t) + ac;
  #pragma unroll
  for (int q = 3; q >= 0; --q) {
    const int cq = (int)cb[q];
    if (cq > 0 && cum_c < krem_in && krem_in <= cum_c + cq) {
      S.sh_dig  = t * 4 + q;
      S.sh_krem = krem_in - cum_c;
    }
    cum_c += cq;
  }
  __syncthreads();
}

// stage-2: 32 sub-bins of bin1 -> final selected-sum given sum-above sa1.
__device__ __forceinline__ float stage2_sel(int krem1, float sa1, RowShared& S) {
  const int t = threadIdx.x;
  if (t < 64) {
    const int cc = (t < 32) ? (int)S.c32[t] : 0;
    const float ss = (t < 32) ? S.s32[t] : 0.f;
    int ci = cc; float si = ss;
    #pragma unroll
    for (int off = 1; off < 64; off <<= 1) {
      const int   co = __shfl_down(ci, off);
      const float so = __shfl_down(si, off);
      if ((t & 63) + off < 64) { ci += co; si += so; }
    }
    const int   above_c = ci - cc;
    const float above_s = si - ss;
    if (t < 32 && cc > 0 && above_c < krem1 && krem1 <= above_c + cc) {
      S.sh_krem = krem1 - above_c;
      S.sh_sa   = sa1 + above_s;
      S.sh_avg  = ss / (float)cc;        // tie-bin average (key-exact)
    }
  }
  __syncthreads();
  return S.sh_sa + (float)S.sh_krem * S.sh_avg;
}

// Normal path: selection over m LDS compact entries (~1800 for s0 rows).
__device__ float select_compact(int m, int k, RowShared& S) {
  const int t = threadIdx.x;
  for (int i = t; i < NB; i += BLK) S.hc[i] = 0u;
  __syncthreads();
  for (int i = t; i < m; i += BLK)
    atomicAdd(&S.hc[S.compact[i] >> 5], 1u);
  __syncthreads();
  unsigned cb[4];
  #pragma unroll
  for (int q = 0; q < 4; ++q) cb[q] = S.hc[4 * t + q];
  selectBin1(cb, k, S);
  const int bin1 = S.sh_dig, krem1 = S.sh_krem;
  if (t < 32) { S.c32[t] = 0u; S.s32[t] = 0.f; }
  __syncthreads();
  float sgt = 0.f;
  for (int i = t; i < m; i += BLK) {
    const unsigned k16 = S.compact[i];
    const int kb = (int)(k16 >> 5);
    if (kb > bin1) sgt += sp16(k16);
    else if (kb == bin1) {
      atomicAdd(&S.c32[k16 & 31u], 1u);
      atomicAdd(&S.s32[k16 & 31u], sp16(k16));
    }
  }
  __syncthreads();
  const float t_sgt = blockSum(sgt, S.fscr);
  return stage2_sel(krem1, t_sgt, S);
}

// Rare exact fallback: full-row global rescan (unfiltered), 2 sweeps.
template<int HW>
__device__ float select_full(const ScaleParams& P, int b, int k, RowShared& S) {
  constexpr int N = 3 * HW;
  const int t = threadIdx.x;
  const float* predb = P.pred + (size_t)b * (NA * KCH) * HW;
  const size_t row = (size_t)b * N;
  for (int i = t; i < NB; i += BLK) S.hc[i] = 0u;
  __syncthreads();
  for (int c8 = t * 8; c8 < N; c8 += BLK * 8) {
    const int a = (c8 >= HW) + (c8 >= 2 * HW);
    const int cell = c8 - a * HW;
    const float* po = predb + (size_t)a * KCH * HW + 4 * HW + cell;
    const float4 o0 = *(const float4*)po;
    const float4 o1 = *(const float4*)(po + 4);
    const uint2 nmv = *(const uint2*)(P.neg + row + c8);
    #pragma unroll
    for (int q = 0; q < 8; ++q) {
      const unsigned nm = ((q < 4) ? (nmv.x >> (8 * q))
                                   : (nmv.y >> (8 * (q - 4)))) & 0xFFu;
      if (nm) {
        const float obj = (q < 4) ? (&o0.x)[q] : (&o1.x)[q - 4];
        atomicAdd(&S.hc[(fkey(__float_as_uint(obj)) >> 16) >> 5], 1u);
      }
    }
  }
  __syncthreads();
  unsigned cb[4];
  #pragma unroll
  for (int q = 0; q < 4; ++q) cb[q] = S.hc[4 * t + q];
  selectBin1(cb, k, S);
  const int bin1 = S.sh_dig, krem1 = S.sh_krem;
  if (t < 32) { S.c32[t] = 0u; S.s32[t] = 0.f; }
  __syncthreads();
  float sgt = 0.f;
  for (int c8 = t * 8; c8 < N; c8 += BLK * 8) {
    const int a = (c8 >= HW) + (c8 >= 2 * HW);
    const int cell = c8 - a * HW;
    const float* po = predb + (size_t)a * KCH * HW + 4 * HW + cell;
    const float4 o0 = *(const float4*)po;
    const float4 o1 = *(const float4*)(po + 4);
    const uint2 nmv = *(const uint2*)(P.neg + row + c8);
    #pragma unroll
    for (int q = 0; q < 8; ++q) {
      const unsigned nm = ((q < 4) ? (nmv.x >> (8 * q))
                                   : (nmv.y >> (8 * (q - 4)))) & 0xFFu;
      if (nm) {
        const float obj = (q < 4) ? (&o0.x)[q] : (&o1.x)[q - 4];
        const unsigned k16 = fkey(__float_as_uint(obj)) >> 16;
        const int kb = (int)(k16 >> 5);
        if (kb > bin1) sgt += sp16(k16);
        else if (kb == bin1) {
          atomicAdd(&S.c32[k16 & 31u], 1u);
          atomicAdd(&S.s32[k16 & 31u], sp16(k16));
        }
      }
    }
  }
  __syncthreads();
  const float t_sgt = blockSum(sgt, S.fscr);
  return stage2_sel(krem1, t_sgt, S);
}

// Whole-row: prefetch-all sweep with batched compact append (no histogram,
// no transcendentals in the hot loop), pos queue + dense pos work, then
// compact selection. part[] written with plain stores.
template<int HW>
__device__ __forceinline__ void row_whole(
    const ScaleParams P, int b, float* part, RowShared& S) {
  constexpr int N = 3 * HW;
  constexpr int ITER = (N + BLK * 8 - 1) / (BLK * 8);
  const int t = threadIdx.x;
  if (t == 0) { S.sh_qn = 0; S.sh_nc = 0; }
  __syncthreads();

  const float* predb = P.pred + (size_t)b * (NA * KCH) * HW;
  const size_t row = (size_t)b * N;
  float nneg = 0.f;

  // ---- sweep, phase A: issue ALL global loads (compile-time unroll) ----
  float4 o0[ITER], o1[ITER];
  uint2  pmv[ITER], nmv[ITER];
  #pragma unroll
  for (int it = 0; it < ITER; ++it) {
    const int c8 = it * (BLK * 8) + t * 8;
    if (c8 < N) {
      const int a = (c8 >= HW) + (c8 >= 2 * HW);
      const int cell = c8 - a * HW;
      const float* po = predb + (size_t)a * KCH * HW + 4 * HW + cell;
      o0[it]  = *(const float4*)po;
      o1[it]  = *(const float4*)(po + 4);
      pmv[it] = *(const uint2*)(P.pos + row + c8);
      nmv[it] = *(const uint2*)(P.neg + row + c8);
    }
  }

  // ---- phase B: popcount nneg, batched compact append, pos queue ----
  #pragma unroll
  for (int it = 0; it < ITER; ++it) {
    const int c8 = it * (BLK * 8) + t * 8;
    if (c8 < N) {
      const unsigned long long nm64 =
          ((unsigned long long)nmv[it].y << 32) | nmv[it].x;
      nneg += (float)__popcll(nm64);       // bool bytes are 0/1
      unsigned k16s[8], cmask = 0u;
      #pragma unroll
      for (int q = 0; q < 8; ++q) {
        const unsigned nm = ((q < 4) ? (nmv[it].x >> (8 * q))
                                     : (nmv[it].y >> (8 * (q - 4)))) & 0xFFu;
        const unsigned pm = ((q < 4) ? (pmv[it].x >> (8 * q))
                                     : (pmv[it].y >> (8 * (q - 4)))) & 0xFFu;
        unsigned k16 = 0u;
        if (nm) {
          k16 = fkey(__float_as_uint((q < 4) ? (&o0[it].x)[q]
                                             : (&o1[it].x)[q - 4])) >> 16;
          if (k16 > LKEY) cmask |= (1u << q);
        }
        k16s[q] = k16;                      // compile-time index: registers
        if (pm) {
          const int idx = atomicAdd(&S.sh_qn, 1);
          if (idx < QCAP) S.queue[idx] = c8 + q;
        }
      }
      if (cmask) {                          // 1 LDS atomic per 8 elements
        const int ci = atomicAdd(&S.sh_nc, (int)__popc(cmask));
        #pragma unroll
        for (int q = 0; q < 8; ++q)
          if ((cmask >> q) & 1u) {
            const int p = ci + (int)__popc(cmask & ((1u << q) - 1u));
            if (p < CCAP) S.compact[p] = (unsigned short)k16s[q];
          }
      }
    }
  }
  __syncthreads();
  const int npos = S.sh_qn;
  const int nc   = S.sh_nc;                // exact count of keys > LKEY
  const int qn = min(npos, QCAP);

  // ---- dense pos-anchor work (~1%): softplus/CE/smooth-L1, L2-hot ----
  float posobj = 0.f, ce = 0.f, loc = 0.f;
  for (int i = t; i < qn; i += BLK) {
    const int j = S.queue[i];
    const int a = (j >= HW) + (j >= 2 * HW);
    const int cell = j - a * HW;
    const float* pa = predb + (size_t)a * KCH * HW;
    posobj += softplus_fast(-pa[4 * HW + cell]);     // sp(x)-x == sp(-x)
    const float c0f = pa[5 * HW + cell];
    const float c1f = pa[6 * HW + cell];
    const float c2f = pa[7 * HW + cell];
    const float m = fmaxf(fmaxf(c0f, c1f), c2f);
    const float e = fexp2((c0f - m) * LOG2E) + fexp2((c1f - m) * LOG2E)
                  + fexp2((c2f - m) * LOG2E);
    const float lse = m + flog2(e) * LN2;
    const int lab = P.labels[row + j];
    ce += lse - ((lab == 0) ? c0f : (lab == 1) ? c1f : c2f);
    const float4 bx = *(const float4*)(P.boxes + (size_t)(row + j) * 4);
    loc += sl1f(pa[0 * HW + cell] - bx.x) + sl1f(pa[1 * HW + cell] - bx.y)
         + sl1f(pa[2 * HW + cell] - bx.z) + sl1f(pa[3 * HW + cell] - bx.w);
  }

  // ---- packed block reduction of 4 scalars (one barrier round) ----
  {
    float v[4] = {nneg, posobj, ce, loc};
    #pragma unroll
    for (int i = 0; i < 4; ++i) {
      #pragma unroll
      for (int off = 32; off > 0; off >>= 1) v[i] += __shfl_down(v[i], off);
    }
    const int lane = t & 63, w = t >> 6;
    __syncthreads();
    if (lane == 0) {
      #pragma unroll
      for (int i = 0; i < 4; ++i) S.wred[w][i] = v[i];
    }
    __syncthreads();
  }
  float red[4];
  #pragma unroll
  for (int i = 0; i < 4; ++i) {
    float acc = 0.f;
    #pragma unroll
    for (int w2 = 0; w2 < NWV; ++w2) acc += S.wred[w2][i];
    red[i] = acc;
  }
  const int k = min(3 * npos, (int)red[0]);

  float sel = 0.f;
  if (k > 0) {  // block-uniform
    if (nc <= CCAP && nc >= k) sel = select_compact(nc, k, S);
    else                       sel = select_full<HW>(P, b, k, S);  // rare, exact
  }

  if (t == 0) {
    const float denom = (float)max(npos, 1);
    part[0] = (red[1] + sel) / denom;               // plain stores:
    part[1] = (npos > 0) ? red[2] / denom : 0.f;    // distinct addresses,
    part[2] = (npos > 0) ? red[3] / (denom * 4.f) : 0.f;  // no RMW contention
  }
}

__global__ void k_zero(unsigned* done) {
  if (threadIdx.x == 0) *done = 0u;
}

// One block per (scale, batch) row; last-arriving block reduces g_part -> out.
__global__ __launch_bounds__(BLK) void k_row(
    ScaleParams p0, ScaleParams p1, ScaleParams p2,
    int B, int R, float invB, float* g_part, unsigned* done, float* out) {
  __shared__ RowShared S;
  const int r = blockIdx.x;
  const int s = (r >= B) + (r >= 2 * B);   // heavy s0 rows dispatched first
  const int b = r - s * B;
  float* part = g_part + (size_t)r * 4;
  if (s == 0)      row_whole<6400>(p0, b, part, S);
  else if (s == 1) row_whole<1600>(p1, b, part, S);
  else             row_whole<400>(p2, b, part, S);

  if (threadIdx.x == 0) {
    __threadfence();                          // release part[] stores
    const unsigned old = atomicAdd(done, 1u); // single-word ticket
    S.sh_flag = (old == (unsigned)(R - 1)) ? 1 : 0;
  }
  __syncthreads();
  if (S.sh_flag) {
    __threadfence();                          // acquire side
    const int t = threadIdx.x;
    float o = 0.f, c = 0.f, l = 0.f;
    for (int i = t; i < R; i += BLK) {
      o += g_part[i * 4 + 0];
      c += g_part[i * 4 + 1];
      l += g_part[i * 4 + 2];
    }
    o = blockSum(o, S.fscr);
    c = blockSum(c, S.fscr);
    l = blockSum(l, S.fscr);
    if (t == 0) {
      out[0] = (o + c + l) * invB;
      out[1] = o * invB;
      out[2] = c * invB;
      out[3] = l * invB;
    }
  }
}

extern "C" void kernel_launch(void* const* d_in, const int* in_sizes, int n_in,
                              void* d_out, int out_size, void* d_ws, size_t ws_size,
                              hipStream_t stream) {
  (void)n_in; (void)out_size; (void)ws_size;

  const int HW0 = 80 * 80, HW1 = 40 * 40, HW2 = 20 * 20;
  const int B = in_sizes[0] / (NA * KCH * HW0);
  const int R = 3 * B;
  const float invB = 1.f / (float)B;

  ScaleParams p0{(const float*)d_in[0],  (const float*)d_in[1],
                 (const int*)d_in[2],    (const uint8_t*)d_in[3],
                 (const uint8_t*)d_in[4], HW0};
  ScaleParams p1{(const float*)d_in[5],  (const float*)d_in[6],
                 (const int*)d_in[7],    (const uint8_t*)d_in[8],
                 (const uint8_t*)d_in[9], HW1};
  ScaleParams p2{(const float*)d_in[10], (const float*)d_in[11],
                 (const int*)d_in[12],   (const uint8_t*)d_in[13],
                 (const uint8_t*)d_in[14], HW2};

  float* out = (float*)d_out;
  unsigned* done = (unsigned*)d_ws;
  float* g_part = (float*)((char*)d_ws + 256);   // R*4 floats, plain stores

  k_zero<<<1, 64, 0, stream>>>(done);
  k_row<<<R, BLK, 0, stream>>>(p0, p1, p2, B, R, invB, g_part, done, out);
}

// Round 22
// 26.903 us; speedup vs baseline: 1.2645x; 1.1440x over previous
//
#include <hip/hip_runtime.h>
#include <stdint.h>

#define NA   3
#define KCH  8       // 5 + NUM_CLASSES
#define BLK  512
#define NWV  (BLK / 64)
#define NB   2048    // stage-1 bins: key16 >> 5 (sign+8exp+2mant)
#define MAXN 19200   // 3 * 80 * 80
#define QCAP 512
#define LKEY 0xBFA8u // raw-obj key16 rung; hist prefilter (runtime-verified)

#define LOG2E 1.4426950408889634f
#define LN2   0.6931471805599453f

struct ScaleParams {
  const float*   pred;    // (B, 24, H, W)
  const float*   boxes;   // (B, N, 4)
  const int*     labels;  // (B, N)
  const uint8_t* pos;     // (B, N) bool
  const uint8_t* neg;     // (B, N) bool
  int HW;
};

__device__ __forceinline__ float fexp2(float x) { return __builtin_amdgcn_exp2f(x); }
__device__ __forceinline__ float flog2(float x) { return __builtin_amdgcn_logf(x); }

// logaddexp(0,x) = max(x,0) + log1p(exp(-|x|)); native exp2/log2, ~1e-6 rel
__device__ __forceinline__ float softplus_fast(float x) {
  const float t = fexp2(-fabsf(x) * LOG2E);
  return fmaxf(x, 0.f) + flog2(1.f + t) * LN2;
}

__device__ __forceinline__ float sl1f(float d) {
  float ad = fabsf(d);
  return (ad < 1.f) ? 0.5f * d * d : ad - 0.5f;
}

// order-preserving float->uint key (larger float => larger key)
__device__ __forceinline__ unsigned fkey(unsigned u) {
  return (u & 0x80000000u) ? ~u : (u | 0x80000000u);
}
__device__ __forceinline__ unsigned funkey(unsigned k) {
  return (k & 0x80000000u) ? (k & 0x7FFFFFFFu) : ~k;
}

// reconstruct approx value from 16-bit key (midpoint of the key interval)
__device__ __forceinline__ float recon16(unsigned k16) {
  return __uint_as_float(funkey((k16 << 16) | 0x8000u));
}

__device__ __forceinline__ float blockSum(float v, float* scr) {
  #pragma unroll
  for (int off = 32; off > 0; off >>= 1) v += __shfl_down(v, off);
  const int lane = threadIdx.x & 63, w = threadIdx.x >> 6;
  __syncthreads();                       // protect scr reuse
  if (lane == 0) scr[w] = v;
  __syncthreads();
  float r = 0.f;
  #pragma unroll
  for (int i = 0; i < NWV; ++i) r += scr[i];   // same-address broadcast
  return r;
}

// Stage-1 select: per-thread 4 consecutive bins (counts only) of ascending-key
// hist; find bin holding the krem-th LARGEST and remaining count inside it.
__device__ __forceinline__ void selectBin1(const unsigned* cb, int krem_in,
    int* iwav, int* sh_dig, int* sh_krem) {
  const int t = threadIdx.x, lane = t & 63, w = t >> 6;
  const int c_t = (int)(cb[0] + cb[1] + cb[2] + cb[3]);
  int ci = c_t;                          // wave inclusive suffix scan
  #pragma unroll
  for (int off = 1; off < 64; off <<= 1) {
    const int co = __shfl_down(ci, off);
    if (lane + off < 64) ci += co;
  }
  __syncthreads();                       // protect iwav reuse
  if (lane == 0) iwav[w] = ci;
  __syncthreads();
  int ac = 0;
  #pragma unroll
  for (int w2 = 0; w2 < NWV; ++w2) if (w2 > w) ac += iwav[w2];
  int cum_c = (ci - c_t) + ac;           // count strictly above thread's top bin
  #pragma unroll
  for (int q = 3; q >= 0; --q) {
    const int cq = (int)cb[q];
    if (cq > 0 && cum_c < krem_in && krem_in <= cum_c + cq) {  // unique bracket
      *sh_dig  = t * 4 + q;
      *sh_krem = krem_in - cum_c;
    }
    cum_c += cq;
  }
  __syncthreads();
}

__global__ void k_zero(unsigned* done) {
  if (threadIdx.x == 0) *done = 0u;
}

struct RowShared {
  unsigned short keys[MAXN];   // 38.4 KB (0 = not-neg; sp keys >= 0x8000)
  unsigned hc[NB];             // 8 KB
  int      queue[QCAP];
  int      sh_qn;
  int      iwav[NWV];
  float    fscr[NWV];
  float    wred[NWV][5];       // packed block-reduction scratch
  int      sh_dig, sh_krem;
  float    sh_sa, sh_avg;
  int      sh_flag;
  unsigned c32[32];
  float    s32[32];
};

// Whole-row processing, compile-time N (round-16 structure, the proven best):
// prefetch-all sweep, keys->LDS + rung-filtered count hist, LDS-only sweep 2,
// 2-stage select. Emits (obj, cls, loc) via PLAIN STORES to part[0..2].
template<int N>
__device__ __forceinline__ void row_impl(
    const ScaleParams P, int b, float* part, RowShared& S) {
  constexpr int HW = N / 3;
  constexpr int ITER = (N + BLK * 8 - 1) / (BLK * 8);
  const int t = threadIdx.x;

  for (int i = t; i < NB; i += BLK) S.hc[i] = 0u;
  if (t == 0) S.sh_qn = 0;
  __syncthreads();

  const float* predb = P.pred + (size_t)b * (NA * KCH) * HW;
  const size_t row = (size_t)b * N;
  float nneg = 0.f;
  int above = 0;

  // ---- sweep 1, phase A: issue ALL global loads (compile-time unroll) ----
  float4 o0[ITER], o1[ITER];
  uint2  pmv[ITER], nmv[ITER];
  #pragma unroll
  for (int it = 0; it < ITER; ++it) {
    const int c8 = it * (BLK * 8) + t * 8;
    if (c8 < N) {
      const int a = (c8 >= HW) + (c8 >= 2 * HW);
      const int cell = c8 - a * HW;
      const float* po = predb + (size_t)a * KCH * HW + 4 * HW + cell;
      o0[it]  = *(const float4*)po;
      o1[it]  = *(const float4*)(po + 4);
      pmv[it] = *(const uint2*)(P.pos + row + c8);
      nmv[it] = *(const uint2*)(P.neg + row + c8);
    }
  }

  // ---- sweep 1, phase B: keys -> LDS, filtered count hist, pos queue ----
  #pragma unroll
  for (int it = 0; it < ITER; ++it) {
    const int c8 = it * (BLK * 8) + t * 8;
    if (c8 < N) {
      const unsigned long long nm64 =
          ((unsigned long long)nmv[it].y << 32) | nmv[it].x;
      nneg += (float)__popcll(nm64);       // bool bytes are 0/1
      unsigned kk[8];
      #pragma unroll
      for (int q = 0; q < 8; ++q) {
        const float obj = (q < 4) ? (&o0[it].x)[q] : (&o1[it].x)[q - 4];
        const unsigned nm = ((q < 4) ? (nmv[it].x >> (8 * q))
                                     : (nmv[it].y >> (8 * (q - 4)))) & 0xFFu;
        const unsigned pm = ((q < 4) ? (pmv[it].x >> (8 * q))
                                     : (pmv[it].y >> (8 * (q - 4)))) & 0xFFu;
        unsigned k16 = 0u;
        if (nm) {
          k16 = fkey(__float_as_uint(obj)) >> 16;   // sp>=0 => k16>=0x8000, never 0
          if (k16 > LKEY) {                // prefilter: ~16% do atomics
            ++above;
            atomicAdd(&S.hc[k16 >> 5], 1u);
          }
        }
        kk[q] = k16;
        if (pm) {
          const int idx = atomicAdd(&S.sh_qn, 1);
          if (idx < QCAP) S.queue[idx] = c8 + q;
        }
      }
      uint4 kv;
      kv.x = kk[0] | (kk[1] << 16); kv.y = kk[2] | (kk[3] << 16);
      kv.z = kk[4] | (kk[5] << 16); kv.w = kk[6] | (kk[7] << 16);
      *reinterpret_cast<uint4*>(&S.keys[c8]) = kv;
    }
  }
  __syncthreads();
  const int npos = S.sh_qn;
  const int qn = min(npos, QCAP);

  // ---- dense pos-anchor work (~1%): softplus/CE/smooth-L1, L2-hot ----
  float posobj = 0.f, ce = 0.f, loc = 0.f;
  for (int i = t; i < qn; i += BLK) {
    const int j = S.queue[i];
    const int a = (j >= HW) + (j >= 2 * HW);
    const int cell = j - a * HW;
    const float* pa = predb + (size_t)a * KCH * HW;
    posobj += softplus_fast(-pa[4 * HW + cell]);     // sp(x)-x == sp(-x)
    const float c0f = pa[5 * HW + cell];
    const float c1f = pa[6 * HW + cell];
    const float c2f = pa[7 * HW + cell];
    const float m = fmaxf(fmaxf(c0f, c1f), c2f);
    const float e = fexp2((c0f - m) * LOG2E) + fexp2((c1f - m) * LOG2E)
                  + fexp2((c2f - m) * LOG2E);
    const float lse = m + flog2(e) * LN2;
    const int lab = P.labels[row + j];
    ce += lse - ((lab == 0) ? c0f : (lab == 1) ? c1f : c2f);
    const float4 bx = *(const float4*)(P.boxes + (size_t)(row + j) * 4);
    loc += sl1f(pa[0 * HW + cell] - bx.x) + sl1f(pa[1 * HW + cell] - bx.y)
         + sl1f(pa[2 * HW + cell] - bx.z) + sl1f(pa[3 * HW + cell] - bx.w);
  }

  // ---- packed block reduction of 5 scalars (one barrier round) ----
  {
    float v[5] = {nneg, posobj, ce, loc, (float)above};
    #pragma unroll
    for (int i = 0; i < 5; ++i) {
      #pragma unroll
      for (int off = 32; off > 0; off >>= 1) v[i] += __shfl_down(v[i], off);
    }
    const int lane = t & 63, w = t >> 6;
    __syncthreads();
    if (lane == 0) {
      #pragma unroll
      for (int i = 0; i < 5; ++i) S.wred[w][i] = v[i];
    }
    __syncthreads();
  }
  float red[5];
  #pragma unroll
  for (int i = 0; i < 5; ++i) {
    float acc = 0.f;
    #pragma unroll
    for (int w2 = 0; w2 < NWV; ++w2) acc += S.wred[w2][i];
    red[i] = acc;
  }
  const float t_po = red[1], t_ce = red[2], t_lc = red[3];
  const int t_above = (int)red[4];
  const int k = min(3 * npos, (int)red[0]);

  float sel = 0.f;
  if (k > 0) {  // block-uniform
    unsigned Lcur = LKEY;
    if (t_above < k) {
      // rare exact fallback: complete the histogram for keys <= LKEY
      #pragma unroll
      for (int it = 0; it < ITER; ++it) {
        const int c8 = it * (BLK * 8) + t * 8;
        if (c8 < N) {
          const uint4 kv = *reinterpret_cast<const uint4*>(&S.keys[c8]);
          const unsigned ks[8] = {kv.x & 0xFFFFu, kv.x >> 16, kv.y & 0xFFFFu,
                                  kv.y >> 16,     kv.z & 0xFFFFu, kv.z >> 16,
                                  kv.w & 0xFFFFu, kv.w >> 16};
          #pragma unroll
          for (int q = 0; q < 8; ++q)
            if (ks[q] && ks[q] <= LKEY) atomicAdd(&S.hc[ks[q] >> 5], 1u);
        }
      }
      __syncthreads();
      Lcur = 0u;
    }

    // ---- stage 1: 11-bit bins, counts only ----
    unsigned cb[4];
    #pragma unroll
    for (int q = 0; q < 4; ++q) cb[q] = S.hc[4 * t + q];
    selectBin1(cb, k, S.iwav, &S.sh_dig, &S.sh_krem);
    const int bin1 = S.sh_dig; const int krem1 = S.sh_krem;

    if (t < 32) { S.c32[t] = 0u; S.s32[t] = 0.f; }
    __syncthreads();

    // ---- sweep 2 (LDS only): sum above bin1; 32-bin refine inside bin1 ----
    float sgt = 0.f;
    #pragma unroll
    for (int it = 0; it < ITER; ++it) {
      const int c8 = it * (BLK * 8) + t * 8;
      if (c8 < N) {
        const uint4 kv = *reinterpret_cast<const uint4*>(&S.keys[c8]);
        const unsigned ks[8] = {kv.x & 0xFFFFu, kv.x >> 16, kv.y & 0xFFFFu,
                                kv.y >> 16,     kv.z & 0xFFFFu, kv.z >> 16,
                                kv.w & 0xFFFFu, kv.w >> 16};
        #pragma unroll
        for (int q = 0; q < 8; ++q) {
          const unsigned k16 = ks[q];
          if (!k16) continue;
          const int kb = (int)(k16 >> 5);
          if (kb > bin1) sgt += softplus_fast(recon16(k16));     // ~3%
          else if (kb == bin1 && k16 > Lcur) {  // match bracket's counts
            atomicAdd(&S.c32[k16 & 31u], 1u);
            atomicAdd(&S.s32[k16 & 31u], softplus_fast(recon16(k16)));
          }
        }
      }
    }
    __syncthreads();
    const float t_sgt = blockSum(sgt, S.fscr);

    // ---- stage 2: 32 bins, one wave (lanes >=32 carry zeros) ----
    if (t < 64) {
      const int cc = (t < 32) ? (int)S.c32[t] : 0;
      const float ss = (t < 32) ? S.s32[t] : 0.f;
      int ci = cc; float si = ss;
      #pragma unroll
      for (int off = 1; off < 64; off <<= 1) {
        const int   co = __shfl_down(ci, off);
        const float so = __shfl_down(si, off);
        if ((t & 63) + off < 64) { ci += co; si += so; }
      }
      const int   above_c = ci - cc;     // count in bins strictly above t
      const float above_s = si - ss;
      if (t < 32 && cc > 0 && above_c < krem1 && krem1 <= above_c + cc) {
        S.sh_krem = krem1 - above_c;
        S.sh_sa   = t_sgt + above_s;
        S.sh_avg  = ss / (float)cc;      // tie-bin average (exact at key level)
      }
    }
    __syncthreads();
    sel = S.sh_sa + (float)S.sh_krem * S.sh_avg;
  }

  if (t == 0) {
    const float denom = (float)max(npos, 1);
    part[0] = (t_po + sel) / denom;                       // plain stores:
    part[1] = (npos > 0) ? t_ce / denom : 0.f;            // distinct addresses,
    part[2] = (npos > 0) ? t_lc / (denom * 4.f) : 0.f;    // no RMW contention
  }
}

// One block per (scale, batch) row; last-arriving block reduces g_part -> out.
__global__ __launch_bounds__(BLK) void k_row(
    ScaleParams p0, ScaleParams p1, ScaleParams p2,
    int B, int R, float invB, float* g_part, unsigned* done, float* out) {
  __shared__ RowShared S;
  const int r = blockIdx.x;
  const int s = (r >= B) + (r >= 2 * B);   // heavy s0 rows dispatched first
  const int b = r - s * B;
  float* part = g_part + (size_t)r * 4;
  if (s == 0)      row_impl<19200>(p0, b, part, S);
  else if (s == 1) row_impl<4800>(p1, b, part, S);
  else             row_impl<1200>(p2, b, part, S);

  if (threadIdx.x == 0) {
    __threadfence();                          // release part[] stores
    const unsigned old = atomicAdd(done, 1u); // single-word ticket
    S.sh_flag = (old == (unsigned)(R - 1)) ? 1 : 0;
  }
  __syncthreads();
  if (S.sh_flag) {
    __threadfence();                          // acquire side
    const int t = threadIdx.x;
    float o = 0.f, c = 0.f, l = 0.f;
    for (int i = t; i < R; i += BLK) {
      const float4 p = *(const float4*)&g_part[i * 4];   // vectorized
      o += p.x; c += p.y; l += p.z;
    }
    o = blockSum(o, S.fscr);
    c = blockSum(c, S.fscr);
    l = blockSum(l, S.fscr);
    if (t == 0) {
      out[0] = (o + c + l) * invB;
      out[1] = o * invB;
      out[2] = c * invB;
      out[3] = l * invB;
    }
  }
}

extern "C" void kernel_launch(void* const* d_in, const int* in_sizes, int n_in,
                              void* d_out, int out_size, void* d_ws, size_t ws_size,
                              hipStream_t stream) {
  (void)n_in; (void)out_size; (void)ws_size;

  const int HW0 = 80 * 80, HW1 = 40 * 40, HW2 = 20 * 20;
  const int B = in_sizes[0] / (NA * KCH * HW0);
  const int R = 3 * B;
  const float invB = 1.f / (float)B;

  ScaleParams p0{(const float*)d_in[0],  (const float*)d_in[1],
                 (const int*)d_in[2],    (const uint8_t*)d_in[3],
                 (const uint8_t*)d_in[4], HW0};
  ScaleParams p1{(const float*)d_in[5],  (const float*)d_in[6],
                 (const int*)d_in[7],    (const uint8_t*)d_in[8],
                 (const uint8_t*)d_in[9], HW1};
  ScaleParams p2{(const float*)d_in[10], (const float*)d_in[11],
                 (const int*)d_in[12],   (const uint8_t*)d_in[13],
                 (const uint8_t*)d_in[14], HW2};

  float* out = (float*)d_out;
  unsigned* done = (unsigned*)d_ws;
  float* g_part = (float*)((char*)d_ws + 256);   // R*4 floats, plain stores

  k_zero<<<1, 64, 0, stream>>>(done);
  k_row<<<R, BLK, 0, stream>>>(p0, p1, p2, B, R, invB, g_part, done, out);
}